// Round 1
// baseline (1499.338 us; speedup 1.0000x reference)
//
#include <hip/hip_runtime.h>
#include <hip/hip_bf16.h>

#define N_NODES_C 100000
#define N_EDGES_C 1200000

// ---------------- deg: count incoming edges at dst ----------------
__global__ void deg_kernel(const int* __restrict__ dst, float* __restrict__ deg, int nE) {
    int e = blockIdx.x * blockDim.x + threadIdx.x;
    if (e < nE) atomicAdd(&deg[dst[e]], 1.0f);
}

// ---------------- lin1: hlin = x @ W1  (x:[N,5], W1:[5,64]) ----------------
__global__ void lin1_kernel(const float* __restrict__ x, const float* __restrict__ W1,
                            float* __restrict__ hlin, int nN) {
    __shared__ float Ws[320];
    int tid = threadIdx.x;
    if (tid < 256) Ws[tid] = W1[tid];
    if (tid < 64)  Ws[256 + tid] = W1[256 + tid];
    __syncthreads();
    int node = blockIdx.x * 4 + (tid >> 6);
    int j = tid & 63;
    if (node < nN) {
        const float* xr = x + node * 5;
        float acc = xr[0] * Ws[j]
                  + xr[1] * Ws[64 + j]
                  + xr[2] * Ws[128 + j]
                  + xr[3] * Ws[192 + j]
                  + xr[4] * Ws[256 + j];
        hlin[node * 64 + j] = acc;
    }
}

// ---------------- scatter: hagg[dst] += norm * hlin[src], 1 wave = 1 edge ----------------
__global__ void scatter_kernel(const int* __restrict__ src, const int* __restrict__ dst,
                               const float* __restrict__ deg,
                               const float* __restrict__ hlin, float* __restrict__ hagg,
                               int nE) {
    int tid = threadIdx.x;
    int e = blockIdx.x * 4 + (tid >> 6);
    int j = tid & 63;
    if (e < nE) {
        int s = src[e];
        int d = dst[e];
        float w = rsqrtf((deg[s] + 1.0f) * (deg[d] + 1.0f));
        atomicAdd(&hagg[d * 64 + j], w * hlin[s * 64 + j]);
    }
}

// ---------------- final1: h1 = relu(hagg + hlin/deg + b) ----------------
__global__ void final1_kernel(const float* __restrict__ hagg, const float* __restrict__ hlin,
                              const float* __restrict__ deg, const float* __restrict__ b,
                              float* __restrict__ h1, int nN) {
    int idx = blockIdx.x * 256 + threadIdx.x;
    int node = idx >> 6;
    int j = idx & 63;
    if (node < nN) {
        float v = hagg[idx] + hlin[idx] / (deg[node] + 1.0f) + b[j];
        h1[idx] = fmaxf(v, 0.0f);
    }
}

// ---------------- lin2: hlin = h1 @ W2  (h1:[N,64], W2:[64,64]) ----------------
__global__ void lin2_kernel(const float* __restrict__ h1, const float* __restrict__ W2,
                            float* __restrict__ hlin, int nN) {
    __shared__ float Ws[64 * 64];
    __shared__ float rows[4][64];
    int tid = threadIdx.x;
    for (int i = tid; i < 4096; i += 256) Ws[i] = W2[i];
    int base = blockIdx.x * 4;
    int n = tid >> 6;
    int j = tid & 63;
    int node = base + n;
    int ldnode = node < nN ? node : (nN - 1);
    rows[n][j] = h1[ldnode * 64 + j];
    __syncthreads();
    float acc = 0.0f;
#pragma unroll
    for (int k = 0; k < 64; ++k) acc += rows[n][k] * Ws[k * 64 + j];
    if (node < nN) hlin[node * 64 + j] = acc;
}

// ---------------- final2: h2 = relu(hagg + hlin/deg + b); colsum += h2 (for mean) ----------------
__global__ void final2_kernel(const float* __restrict__ hagg, const float* __restrict__ hlin,
                              const float* __restrict__ deg, const float* __restrict__ b,
                              float* __restrict__ colsum, int nN) {
    __shared__ float sm[256];
    int tid = threadIdx.x;
    int idx = blockIdx.x * 256 + tid;
    int node = idx >> 6;
    int j = tid & 63;
    float v = 0.0f;
    if (node < nN) {
        v = hagg[idx] + hlin[idx] / (deg[node] + 1.0f) + b[j];
        v = fmaxf(v, 0.0f);
    }
    sm[tid] = v;
    __syncthreads();
    if (tid < 64) {
        float s = sm[tid] + sm[tid + 64] + sm[tid + 128] + sm[tid + 192];
        atomicAdd(&colsum[tid], s);
    }
}

// ---------------- gfeat: reductions over x columns ----------------
// gs layout: [0]=sum x0*mask, [1]=sum x1*mask, [2]=sum x2, [3]=sum x3, [4]=sum x4, [5]=msum
__global__ void gfeat_kernel(const float* __restrict__ x, float* __restrict__ gs, int nN) {
    int tid = threadIdx.x;
    int i = blockIdx.x * 256 + tid;
    float s0 = 0, s1 = 0, s2 = 0, s3 = 0, s4 = 0, s5 = 0;
    if (i < nN) {
        const float* xr = x + i * 5;
        float x0 = xr[0], x1 = xr[1], x2 = xr[2], x3 = xr[3], x4 = xr[4];
        float m = (x2 == 1.0f) ? 1.0f : 0.0f;
        s0 = x0 * m; s1 = x1 * m; s2 = x2; s3 = x3; s4 = x4; s5 = m;
    }
#pragma unroll
    for (int off = 32; off > 0; off >>= 1) {
        s0 += __shfl_down(s0, off);
        s1 += __shfl_down(s1, off);
        s2 += __shfl_down(s2, off);
        s3 += __shfl_down(s3, off);
        s4 += __shfl_down(s4, off);
        s5 += __shfl_down(s5, off);
    }
    if ((tid & 63) == 0) {
        atomicAdd(&gs[0], s0);
        atomicAdd(&gs[1], s1);
        atomicAdd(&gs[2], s2);
        atomicAdd(&gs[3], s3);
        atomicAdd(&gs[4], s4);
        atomicAdd(&gs[5], s5);
    }
}

// ---------------- head: embedding/g concat -> MLP 71->32->2 -> 2+4*sigmoid ----------------
__global__ void head_kernel(const float* __restrict__ colsum, const float* __restrict__ gs,
                            const float* __restrict__ Wp1, const float* __restrict__ bp1,
                            const float* __restrict__ Wp2, const float* __restrict__ bp2,
                            const int* __restrict__ T, const int* __restrict__ Tmax,
                            float* __restrict__ out) {
    __shared__ float e[71];
    __shared__ float hid[32];
    int tid = threadIdx.x;
    if (tid < 64) e[tid] = colsum[tid] * (1.0f / (float)N_NODES_C);
    else if (tid == 64) e[64] = gs[2];                       // n_comp
    else if (tid == 65) e[65] = gs[3];                       // n_AND
    else if (tid == 66) e[66] = gs[4];                       // n_OR
    else if (tid == 67) e[67] = gs[3] + gs[4];               // depth
    else if (tid == 68) {
        float m = gs[5];
        e[68] = (m > 0.0f) ? gs[0] / fmaxf(m, 1.0f) : 0.0f;  // avg_lambda
    } else if (tid == 69) {
        float m = gs[5];
        e[69] = (m > 0.0f) ? gs[1] / fmaxf(m, 1.0f) : 0.0f;  // avg_mu
    } else if (tid == 70) {
        e[70] = (float)T[0] / (float)Tmax[0];                // T_norm
    }
    __syncthreads();
    if (tid < 32) {
        float acc = bp1[tid];
        for (int i = 0; i < 71; ++i) acc += e[i] * Wp1[i * 32 + tid];
        hid[tid] = fmaxf(acc, 0.0f);
    }
    __syncthreads();
    if (tid < 2) {
        float acc = bp2[tid];
        for (int k = 0; k < 32; ++k) acc += hid[k] * Wp2[k * 2 + tid];
        out[tid] = 2.0f + 4.0f / (1.0f + expf(-acc));
    }
}

extern "C" void kernel_launch(void* const* d_in, const int* in_sizes, int n_in,
                              void* d_out, int out_size, void* d_ws, size_t ws_size,
                              hipStream_t stream) {
    const float* x    = (const float*)d_in[0];
    const int*   ei   = (const int*)d_in[1];
    const float* W1   = (const float*)d_in[2];
    const float* b1   = (const float*)d_in[3];
    const float* W2   = (const float*)d_in[4];
    const float* b2   = (const float*)d_in[5];
    const float* Wp1  = (const float*)d_in[6];
    const float* bp1  = (const float*)d_in[7];
    const float* Wp2  = (const float*)d_in[8];
    const float* bp2  = (const float*)d_in[9];
    const int*   T    = (const int*)d_in[10];
    const int*   Tmax = (const int*)d_in[11];
    float* out = (float*)d_out;

    const int nN = N_NODES_C;
    const int nE = N_EDGES_C;
    const int* src = ei;
    const int* dst = ei + nE;

    const size_t H_BYTES = (size_t)nN * 64 * sizeof(float);  // 25.6 MB
    char* ws = (char*)d_ws;
    float* deg    = (float*)(ws);
    float* hlin   = (float*)(ws + 512 * 1024);
    float* hagg   = (float*)(ws + 512 * 1024 + H_BYTES);
    float* h1     = (float*)(ws + 512 * 1024 + 2 * H_BYTES);
    float* colsum = (float*)(ws + 512 * 1024 + 3 * H_BYTES);
    float* gs     = (float*)(ws + 512 * 1024 + 3 * H_BYTES + 256);

    hipMemsetAsync(deg, 0, nN * sizeof(float), stream);
    hipMemsetAsync(hagg, 0, H_BYTES, stream);
    hipMemsetAsync(colsum, 0, 256 + 32, stream);  // colsum[64] + gs[6..8]

    // degree
    deg_kernel<<<(nE + 255) / 256, 256, 0, stream>>>(dst, deg, nE);

    // layer 1
    lin1_kernel<<<(nN + 3) / 4, 256, 0, stream>>>(x, W1, hlin, nN);
    scatter_kernel<<<(nE + 3) / 4, 256, 0, stream>>>(src, dst, deg, hlin, hagg, nE);
    final1_kernel<<<(nN + 3) / 4, 256, 0, stream>>>(hagg, hlin, deg, b1, h1, nN);

    // layer 2
    hipMemsetAsync(hagg, 0, H_BYTES, stream);
    lin2_kernel<<<(nN + 3) / 4, 256, 0, stream>>>(h1, W2, hlin, nN);
    scatter_kernel<<<(nE + 3) / 4, 256, 0, stream>>>(src, dst, deg, hlin, hagg, nE);

    // global features (independent, reads x)
    gfeat_kernel<<<(nN + 255) / 256, 256, 0, stream>>>(x, gs, nN);

    // finalize layer 2 + column sums for mean pool
    final2_kernel<<<(nN + 3) / 4, 256, 0, stream>>>(hagg, hlin, deg, b2, colsum, nN);

    // head MLP
    head_kernel<<<1, 128, 0, stream>>>(colsum, gs, Wp1, bp1, Wp2, bp2, T, Tmax, out);
}

// Round 2
// 935.029 us; speedup vs baseline: 1.6035x; 1.6035x over previous
//
#include <hip/hip_runtime.h>
#include <hip/hip_bf16.h>

#define N_NODES_C 100000
#define N_EDGES_C 1200000

// ---------------- deg: count incoming edges at dst ----------------
__global__ void deg_kernel(const int* __restrict__ dst, float* __restrict__ deg, int nE) {
    int e = blockIdx.x * blockDim.x + threadIdx.x;
    if (e < nE) atomicAdd(&deg[dst[e]], 1.0f);
}

// ---------------- lin1: hlin = x @ W1  (x:[N,5], W1:[5,64]) ----------------
__global__ void lin1_kernel(const float* __restrict__ x, const float* __restrict__ W1,
                            float* __restrict__ hlin, int nN) {
    __shared__ float Ws[320];
    int tid = threadIdx.x;
    if (tid < 256) Ws[tid] = W1[tid];
    if (tid < 64)  Ws[256 + tid] = W1[256 + tid];
    __syncthreads();
    int node = blockIdx.x * 4 + (tid >> 6);
    int j = tid & 63;
    if (node < nN) {
        const float* xr = x + node * 5;
        float acc = xr[0] * Ws[j]
                  + xr[1] * Ws[64 + j]
                  + xr[2] * Ws[128 + j]
                  + xr[3] * Ws[192 + j]
                  + xr[4] * Ws[256 + j];
        hlin[node * 64 + j] = acc;
    }
}

// ---------------- scatter: hagg[dst] += norm * hlin[src], 1 wave = 1 edge ----------------
__global__ void scatter_kernel(const int* __restrict__ src, const int* __restrict__ dst,
                               const float* __restrict__ deg,
                               const float* __restrict__ hlin, float* __restrict__ hagg,
                               int nE) {
    int tid = threadIdx.x;
    int e = blockIdx.x * 4 + (tid >> 6);
    int j = tid & 63;
    if (e < nE) {
        int s = src[e];
        int d = dst[e];
        float w = rsqrtf((deg[s] + 1.0f) * (deg[d] + 1.0f));
        atomicAdd(&hagg[d * 64 + j], w * hlin[s * 64 + j]);
    }
}

// ---------------- final1: h1 = relu(hagg + hlin/deg + b) ----------------
__global__ void final1_kernel(const float* __restrict__ hagg, const float* __restrict__ hlin,
                              const float* __restrict__ deg, const float* __restrict__ b,
                              float* __restrict__ h1, int nN) {
    int idx = blockIdx.x * 256 + threadIdx.x;
    int node = idx >> 6;
    int j = idx & 63;
    if (node < nN) {
        float v = hagg[idx] + hlin[idx] / (deg[node] + 1.0f) + b[j];
        h1[idx] = fmaxf(v, 0.0f);
    }
}

// ---------------- lin2: hlin = h1 @ W2  (h1:[N,64], W2:[64,64]) ----------------
__global__ void lin2_kernel(const float* __restrict__ h1, const float* __restrict__ W2,
                            float* __restrict__ hlin, int nN) {
    __shared__ float Ws[64 * 64];
    __shared__ float rows[4][64];
    int tid = threadIdx.x;
    for (int i = tid; i < 4096; i += 256) Ws[i] = W2[i];
    int base = blockIdx.x * 4;
    int n = tid >> 6;
    int j = tid & 63;
    int node = base + n;
    int ldnode = node < nN ? node : (nN - 1);
    rows[n][j] = h1[ldnode * 64 + j];
    __syncthreads();
    float acc = 0.0f;
#pragma unroll
    for (int k = 0; k < 64; ++k) acc += rows[n][k] * Ws[k * 64 + j];
    if (node < nN) hlin[node * 64 + j] = acc;
}

// ---------------- final2: grid-stride; per-block partial colsum, 1 atomic/feature/block ----------------
__global__ void final2_kernel(const float* __restrict__ hagg, const float* __restrict__ hlin,
                              const float* __restrict__ deg, const float* __restrict__ b,
                              float* __restrict__ colsum, int nN) {
    __shared__ float sm[256];
    int tid = threadIdx.x;
    int j = tid & 63;
    int sub = tid >> 6;  // 0..3
    float bj = b[j];
    float acc = 0.0f;
    for (int node = blockIdx.x * 4 + sub; node < nN; node += gridDim.x * 4) {
        int idx = node * 64 + j;
        float v = hagg[idx] + hlin[idx] / (deg[node] + 1.0f) + bj;
        acc += fmaxf(v, 0.0f);
    }
    sm[tid] = acc;
    __syncthreads();
    if (tid < 64) {
        float s = sm[tid] + sm[tid + 64] + sm[tid + 128] + sm[tid + 192];
        atomicAdd(&colsum[tid], s);
    }
}

// ---------------- gfeat: reductions over x columns ----------------
// gs layout: [0]=sum x0*mask, [1]=sum x1*mask, [2]=sum x2, [3]=sum x3, [4]=sum x4, [5]=msum
__global__ void gfeat_kernel(const float* __restrict__ x, float* __restrict__ gs, int nN) {
    int tid = threadIdx.x;
    int i = blockIdx.x * 256 + tid;
    float s0 = 0, s1 = 0, s2 = 0, s3 = 0, s4 = 0, s5 = 0;
    if (i < nN) {
        const float* xr = x + i * 5;
        float x0 = xr[0], x1 = xr[1], x2 = xr[2], x3 = xr[3], x4 = xr[4];
        float m = (x2 == 1.0f) ? 1.0f : 0.0f;
        s0 = x0 * m; s1 = x1 * m; s2 = x2; s3 = x3; s4 = x4; s5 = m;
    }
#pragma unroll
    for (int off = 32; off > 0; off >>= 1) {
        s0 += __shfl_down(s0, off);
        s1 += __shfl_down(s1, off);
        s2 += __shfl_down(s2, off);
        s3 += __shfl_down(s3, off);
        s4 += __shfl_down(s4, off);
        s5 += __shfl_down(s5, off);
    }
    if ((tid & 63) == 0) {
        atomicAdd(&gs[0], s0);
        atomicAdd(&gs[1], s1);
        atomicAdd(&gs[2], s2);
        atomicAdd(&gs[3], s3);
        atomicAdd(&gs[4], s4);
        atomicAdd(&gs[5], s5);
    }
}

// ---------------- head: embedding/g concat -> MLP 71->32->2 -> 2+4*sigmoid ----------------
__global__ void head_kernel(const float* __restrict__ colsum, const float* __restrict__ gs,
                            const float* __restrict__ Wp1, const float* __restrict__ bp1,
                            const float* __restrict__ Wp2, const float* __restrict__ bp2,
                            const int* __restrict__ T, const int* __restrict__ Tmax,
                            float* __restrict__ out) {
    __shared__ float e[71];
    __shared__ float hid[32];
    int tid = threadIdx.x;
    if (tid < 64) e[tid] = colsum[tid] * (1.0f / (float)N_NODES_C);
    else if (tid == 64) e[64] = gs[2];                       // n_comp
    else if (tid == 65) e[65] = gs[3];                       // n_AND
    else if (tid == 66) e[66] = gs[4];                       // n_OR
    else if (tid == 67) e[67] = gs[3] + gs[4];               // depth
    else if (tid == 68) {
        float m = gs[5];
        e[68] = (m > 0.0f) ? gs[0] / fmaxf(m, 1.0f) : 0.0f;  // avg_lambda
    } else if (tid == 69) {
        float m = gs[5];
        e[69] = (m > 0.0f) ? gs[1] / fmaxf(m, 1.0f) : 0.0f;  // avg_mu
    } else if (tid == 70) {
        e[70] = (float)T[0] / (float)Tmax[0];                // T_norm
    }
    __syncthreads();
    if (tid < 32) {
        float acc = bp1[tid];
        for (int i = 0; i < 71; ++i) acc += e[i] * Wp1[i * 32 + tid];
        hid[tid] = fmaxf(acc, 0.0f);
    }
    __syncthreads();
    if (tid < 2) {
        float acc = bp2[tid];
        for (int k = 0; k < 32; ++k) acc += hid[k] * Wp2[k * 2 + tid];
        out[tid] = 2.0f + 4.0f / (1.0f + expf(-acc));
    }
}

extern "C" void kernel_launch(void* const* d_in, const int* in_sizes, int n_in,
                              void* d_out, int out_size, void* d_ws, size_t ws_size,
                              hipStream_t stream) {
    const float* x    = (const float*)d_in[0];
    const int*   ei   = (const int*)d_in[1];
    const float* W1   = (const float*)d_in[2];
    const float* b1   = (const float*)d_in[3];
    const float* W2   = (const float*)d_in[4];
    const float* b2   = (const float*)d_in[5];
    const float* Wp1  = (const float*)d_in[6];
    const float* bp1  = (const float*)d_in[7];
    const float* Wp2  = (const float*)d_in[8];
    const float* bp2  = (const float*)d_in[9];
    const int*   T    = (const int*)d_in[10];
    const int*   Tmax = (const int*)d_in[11];
    float* out = (float*)d_out;

    const int nN = N_NODES_C;
    const int nE = N_EDGES_C;
    const int* src = ei;
    const int* dst = ei + nE;

    const size_t H_BYTES = (size_t)nN * 64 * sizeof(float);  // 25.6 MB
    char* ws = (char*)d_ws;
    float* deg    = (float*)(ws);
    float* hlin   = (float*)(ws + 512 * 1024);
    float* hagg   = (float*)(ws + 512 * 1024 + H_BYTES);
    float* h1     = (float*)(ws + 512 * 1024 + 2 * H_BYTES);
    float* colsum = (float*)(ws + 512 * 1024 + 3 * H_BYTES);
    float* gs     = (float*)(ws + 512 * 1024 + 3 * H_BYTES + 256);

    hipMemsetAsync(deg, 0, nN * sizeof(float), stream);
    hipMemsetAsync(hagg, 0, H_BYTES, stream);
    hipMemsetAsync(colsum, 0, 256 + 32, stream);  // colsum[64] + gs[6..8]

    // degree
    deg_kernel<<<(nE + 255) / 256, 256, 0, stream>>>(dst, deg, nE);

    // layer 1
    lin1_kernel<<<(nN + 3) / 4, 256, 0, stream>>>(x, W1, hlin, nN);
    scatter_kernel<<<(nE + 3) / 4, 256, 0, stream>>>(src, dst, deg, hlin, hagg, nE);
    final1_kernel<<<(nN + 3) / 4, 256, 0, stream>>>(hagg, hlin, deg, b1, h1, nN);

    // layer 2
    hipMemsetAsync(hagg, 0, H_BYTES, stream);
    lin2_kernel<<<(nN + 3) / 4, 256, 0, stream>>>(h1, W2, hlin, nN);
    scatter_kernel<<<(nE + 3) / 4, 256, 0, stream>>>(src, dst, deg, hlin, hagg, nE);

    // global features (independent, reads x)
    gfeat_kernel<<<(nN + 255) / 256, 256, 0, stream>>>(x, gs, nN);

    // finalize layer 2 + column sums for mean pool (grid-stride, low atomic contention)
    final2_kernel<<<1024, 256, 0, stream>>>(hagg, hlin, deg, b2, colsum, nN);

    // head MLP
    head_kernel<<<1, 128, 0, stream>>>(colsum, gs, Wp1, bp1, Wp2, bp2, T, Tmax, out);
}

// Round 3
// 562.505 us; speedup vs baseline: 2.6655x; 1.6623x over previous
//
#include <hip/hip_runtime.h>
#include <hip/hip_bf16.h>

#define N_NODES_C 100000
#define N_EDGES_C 1200000

// ---------------- deg: count incoming edges at dst (int) ----------------
__global__ void deg_kernel(const int* __restrict__ dst, int* __restrict__ cnt, int nE) {
    int e = blockIdx.x * blockDim.x + threadIdx.x;
    if (e < nE) atomicAdd(&cnt[dst[e]], 1);
}

// ---------------- bsum: per-1024-chunk sums of cnt ----------------
__global__ void bsum_kernel(const int* __restrict__ cnt, int* __restrict__ bsum, int nN) {
    __shared__ int sm[256];
    int tid = threadIdx.x;
    int base = blockIdx.x * 1024 + tid * 4;
    int s = 0;
#pragma unroll
    for (int k = 0; k < 4; ++k)
        if (base + k < nN) s += cnt[base + k];
    sm[tid] = s;
    __syncthreads();
    for (int off = 128; off > 0; off >>= 1) {
        if (tid < off) sm[tid] += sm[tid + off];
        __syncthreads();
    }
    if (tid == 0) bsum[blockIdx.x] = sm[0];
}

// ---------------- bscan: exclusive scan of block sums (nb <= 128) ----------------
__global__ void bscan_kernel(const int* __restrict__ bsum, int* __restrict__ boff, int nb) {
    __shared__ int sm[128];
    int tid = threadIdx.x;
    sm[tid] = (tid < nb) ? bsum[tid] : 0;
    __syncthreads();
    for (int off = 1; off < 128; off <<= 1) {
        int t = (tid >= off) ? sm[tid - off] : 0;
        __syncthreads();
        sm[tid] += t;
        __syncthreads();
    }
    if (tid < nb) boff[tid] = (tid ? sm[tid - 1] : 0);
}

// ---------------- scan_block: exclusive scan within 1024-chunk + boff -> rowptr ----------------
__global__ void scan_block_kernel(const int* __restrict__ cnt, const int* __restrict__ boff,
                                  int* __restrict__ rowptr, int nN) {
    __shared__ int sm[256];
    int tid = threadIdx.x;
    int base = blockIdx.x * 1024 + tid * 4;
    int v0 = 0, v1 = 0, v2 = 0, v3 = 0;
    if (base + 0 < nN) v0 = cnt[base + 0];
    if (base + 1 < nN) v1 = cnt[base + 1];
    if (base + 2 < nN) v2 = cnt[base + 2];
    if (base + 3 < nN) v3 = cnt[base + 3];
    int tsum = v0 + v1 + v2 + v3;
    sm[tid] = tsum;
    __syncthreads();
    for (int off = 1; off < 256; off <<= 1) {
        int t = (tid >= off) ? sm[tid - off] : 0;
        __syncthreads();
        sm[tid] += t;
        __syncthreads();
    }
    int excl = (tid ? sm[tid - 1] : 0) + boff[blockIdx.x];
    if (base + 0 <= nN) rowptr[base + 0] = excl;
    if (base + 1 <= nN) rowptr[base + 1] = excl + v0;
    if (base + 2 <= nN) rowptr[base + 2] = excl + v0 + v1;
    if (base + 3 <= nN) rowptr[base + 3] = excl + v0 + v1 + v2;
}

// ---------------- prep: dis[i] = rsqrt(cnt[i]+1) ----------------
__global__ void prep_kernel(const int* __restrict__ cnt, float* __restrict__ dis, int nN) {
    int i = blockIdx.x * 256 + threadIdx.x;
    if (i < nN) dis[i] = rsqrtf((float)(cnt[i] + 1));
}

// ---------------- bin: scatter edges into CSR slots with precomputed weights ----------------
__global__ void bin_kernel(const int* __restrict__ src, const int* __restrict__ dst,
                           const float* __restrict__ dis, const int* __restrict__ rowptr,
                           int* __restrict__ fill, int* __restrict__ csr_src,
                           float* __restrict__ csr_w, int nE) {
    int e = blockIdx.x * 256 + threadIdx.x;
    if (e < nE) {
        int s = src[e];
        int d = dst[e];
        int slot = rowptr[d] + atomicAdd(&fill[d], 1);
        csr_src[slot] = s;
        csr_w[slot] = dis[s] * dis[d];
    }
}

// ---------------- lin1: hlin = x @ W1  (x:[N,5], W1:[5,64]) ----------------
__global__ void lin1_kernel(const float* __restrict__ x, const float* __restrict__ W1,
                            float* __restrict__ hlin, int nN) {
    __shared__ float Ws[320];
    int tid = threadIdx.x;
    if (tid < 256) Ws[tid] = W1[tid];
    if (tid < 64)  Ws[256 + tid] = W1[256 + tid];
    __syncthreads();
    int node = blockIdx.x * 4 + (tid >> 6);
    int j = tid & 63;
    if (node < nN) {
        const float* xr = x + node * 5;
        float acc = xr[0] * Ws[j]
                  + xr[1] * Ws[64 + j]
                  + xr[2] * Ws[128 + j]
                  + xr[3] * Ws[192 + j]
                  + xr[4] * Ws[256 + j];
        hlin[node * 64 + j] = acc;
    }
}

// ---------------- gather: per dst node, pull weighted rows; fuse self-loop+bias+relu ----------------
// COLSUM=false: write hout. COLSUM=true: accumulate column sums (striped atomic banks).
template <bool COLSUM>
__global__ void gather_kernel(const int* __restrict__ rowptr, const int* __restrict__ csr_src,
                              const float* __restrict__ csr_w, const float* __restrict__ hlin,
                              const float* __restrict__ b, float* __restrict__ hout,
                              float* __restrict__ colsum, int nN) {
    int tid = threadIdx.x;
    int j = tid & 63;
    int wv = tid >> 6;
    float bj = b[j];
    float colacc = 0.0f;
    for (int node = blockIdx.x * 4 + wv; node < nN; node += gridDim.x * 4) {
        int e0 = rowptr[node];
        int e1 = rowptr[node + 1];
        float acc = 0.0f;
        // software-pipelined: load next edge meta while current row load is in flight
        int s_next = 0;
        float w_next = 0.0f;
        if (e0 < e1) { s_next = csr_src[e0]; w_next = csr_w[e0]; }
        for (int e = e0; e < e1; ++e) {
            int s = s_next;
            float w = w_next;
            if (e + 1 < e1) { s_next = csr_src[e + 1]; w_next = csr_w[e + 1]; }
            acc = fmaf(w, hlin[s * 64 + j], acc);
        }
        float invd = 1.0f / (float)(e1 - e0 + 1);
        float v = acc + hlin[node * 64 + j] * invd + bj;
        v = fmaxf(v, 0.0f);
        if (COLSUM) colacc += v;
        else hout[node * 64 + j] = v;
    }
    if (COLSUM) {
        __shared__ float sm[256];
        sm[tid] = colacc;
        __syncthreads();
        if (tid < 64) {
            float s = sm[tid] + sm[tid + 64] + sm[tid + 128] + sm[tid + 192];
            atomicAdd(&colsum[(blockIdx.x & 15) * 64 + tid], s);
        }
    }
}

// ---------------- lin2: hlin = h1 @ W2  (h1:[N,64], W2:[64,64]) ----------------
__global__ void lin2_kernel(const float* __restrict__ h1, const float* __restrict__ W2,
                            float* __restrict__ hlin, int nN) {
    __shared__ float Ws[64 * 64];
    __shared__ float rows[4][64];
    int tid = threadIdx.x;
    for (int i = tid; i < 4096; i += 256) Ws[i] = W2[i];
    int base = blockIdx.x * 4;
    int n = tid >> 6;
    int j = tid & 63;
    int node = base + n;
    int ldnode = node < nN ? node : (nN - 1);
    rows[n][j] = h1[ldnode * 64 + j];
    __syncthreads();
    float acc = 0.0f;
#pragma unroll
    for (int k = 0; k < 64; ++k) acc += rows[n][k] * Ws[k * 64 + j];
    if (node < nN) hlin[node * 64 + j] = acc;
}

// ---------------- gfeat: reductions over x columns ----------------
// gs layout: [0]=sum x0*mask, [1]=sum x1*mask, [2]=sum x2, [3]=sum x3, [4]=sum x4, [5]=msum
__global__ void gfeat_kernel(const float* __restrict__ x, float* __restrict__ gs, int nN) {
    int tid = threadIdx.x;
    int i = blockIdx.x * 256 + tid;
    float s0 = 0, s1 = 0, s2 = 0, s3 = 0, s4 = 0, s5 = 0;
    if (i < nN) {
        const float* xr = x + i * 5;
        float x0 = xr[0], x1 = xr[1], x2 = xr[2], x3 = xr[3], x4 = xr[4];
        float m = (x2 == 1.0f) ? 1.0f : 0.0f;
        s0 = x0 * m; s1 = x1 * m; s2 = x2; s3 = x3; s4 = x4; s5 = m;
    }
#pragma unroll
    for (int off = 32; off > 0; off >>= 1) {
        s0 += __shfl_down(s0, off);
        s1 += __shfl_down(s1, off);
        s2 += __shfl_down(s2, off);
        s3 += __shfl_down(s3, off);
        s4 += __shfl_down(s4, off);
        s5 += __shfl_down(s5, off);
    }
    if ((tid & 63) == 0) {
        atomicAdd(&gs[0], s0);
        atomicAdd(&gs[1], s1);
        atomicAdd(&gs[2], s2);
        atomicAdd(&gs[3], s3);
        atomicAdd(&gs[4], s4);
        atomicAdd(&gs[5], s5);
    }
}

// ---------------- head: reduce striped colsum; MLP 71->32->2 -> 2+4*sigmoid ----------------
__global__ void head_kernel(const float* __restrict__ colsumB, const float* __restrict__ gs,
                            const float* __restrict__ Wp1, const float* __restrict__ bp1,
                            const float* __restrict__ Wp2, const float* __restrict__ bp2,
                            const int* __restrict__ T, const int* __restrict__ Tmax,
                            float* __restrict__ out) {
    __shared__ float e[71];
    __shared__ float hid[32];
    int tid = threadIdx.x;
    if (tid < 64) {
        float s = 0.0f;
#pragma unroll
        for (int r = 0; r < 16; ++r) s += colsumB[r * 64 + tid];
        e[tid] = s * (1.0f / (float)N_NODES_C);
    }
    else if (tid == 64) e[64] = gs[2];                       // n_comp
    else if (tid == 65) e[65] = gs[3];                       // n_AND
    else if (tid == 66) e[66] = gs[4];                       // n_OR
    else if (tid == 67) e[67] = gs[3] + gs[4];               // depth
    else if (tid == 68) {
        float m = gs[5];
        e[68] = (m > 0.0f) ? gs[0] / fmaxf(m, 1.0f) : 0.0f;  // avg_lambda
    } else if (tid == 69) {
        float m = gs[5];
        e[69] = (m > 0.0f) ? gs[1] / fmaxf(m, 1.0f) : 0.0f;  // avg_mu
    } else if (tid == 70) {
        e[70] = (float)T[0] / (float)Tmax[0];                // T_norm
    }
    __syncthreads();
    if (tid < 32) {
        float acc = bp1[tid];
        for (int i = 0; i < 71; ++i) acc += e[i] * Wp1[i * 32 + tid];
        hid[tid] = fmaxf(acc, 0.0f);
    }
    __syncthreads();
    if (tid < 2) {
        float acc = bp2[tid];
        for (int k = 0; k < 32; ++k) acc += hid[k] * Wp2[k * 2 + tid];
        out[tid] = 2.0f + 4.0f / (1.0f + expf(-acc));
    }
}

extern "C" void kernel_launch(void* const* d_in, const int* in_sizes, int n_in,
                              void* d_out, int out_size, void* d_ws, size_t ws_size,
                              hipStream_t stream) {
    const float* x    = (const float*)d_in[0];
    const int*   ei   = (const int*)d_in[1];
    const float* W1   = (const float*)d_in[2];
    const float* b1   = (const float*)d_in[3];
    const float* W2   = (const float*)d_in[4];
    const float* b2   = (const float*)d_in[5];
    const float* Wp1  = (const float*)d_in[6];
    const float* bp1  = (const float*)d_in[7];
    const float* Wp2  = (const float*)d_in[8];
    const float* bp2  = (const float*)d_in[9];
    const int*   T    = (const int*)d_in[10];
    const int*   Tmax = (const int*)d_in[11];
    float* out = (float*)d_out;

    const int nN = N_NODES_C;
    const int nE = N_EDGES_C;
    const int* src = ei;
    const int* dst = ei + nE;

    char* ws = (char*)d_ws;
    // layout (bytes):
    int*   cnt     = (int*)  (ws + 0);                    // 400000
    int*   fill    = (int*)  (ws + 400000);               // 400000
    float* colsumB = (float*)(ws + 800000);               // 16*64*4 = 4096
    float* gs      = (float*)(ws + 804096);               // 64
    int*   bsum    = (int*)  (ws + 804160);               // 512
    int*   boff    = (int*)  (ws + 804672);               // 512
    int*   rowptr  = (int*)  (ws + 805184);               // 400016
    float* dis     = (float*)(ws + 1205200);              // 400000
    int*   csr_src = (int*)  (ws + 1605200);              // 4.8 MB
    float* csr_w   = (float*)(ws + 6405200);              // 4.8 MB
    float* hlin    = (float*)(ws + 11205200);             // 25.6 MB
    float* h1      = (float*)(ws + 36805200);             // 25.6 MB

    // zero: cnt + fill + colsumB + gs in one shot
    hipMemsetAsync(ws, 0, 804160, stream);

    const int nb = (nN + 1023) / 1024;  // 98

    // CSR build (weights shared by both layers)
    deg_kernel<<<(nE + 255) / 256, 256, 0, stream>>>(dst, cnt, nE);
    bsum_kernel<<<nb, 256, 0, stream>>>(cnt, bsum, nN);
    bscan_kernel<<<1, 128, 0, stream>>>(bsum, boff, nb);
    scan_block_kernel<<<nb, 256, 0, stream>>>(cnt, boff, rowptr, nN);
    prep_kernel<<<(nN + 255) / 256, 256, 0, stream>>>(cnt, dis, nN);
    bin_kernel<<<(nE + 255) / 256, 256, 0, stream>>>(src, dst, dis, rowptr, fill,
                                                     csr_src, csr_w, nE);

    // layer 1: lin + pull-gather (fused self-loop+bias+relu)
    lin1_kernel<<<(nN + 3) / 4, 256, 0, stream>>>(x, W1, hlin, nN);
    gather_kernel<false><<<2048, 256, 0, stream>>>(rowptr, csr_src, csr_w, hlin, b1,
                                                   h1, nullptr, nN);

    // layer 2: lin + pull-gather fused with column-sum (mean pool)
    lin2_kernel<<<(nN + 3) / 4, 256, 0, stream>>>(h1, W2, hlin, nN);
    gather_kernel<true><<<2048, 256, 0, stream>>>(rowptr, csr_src, csr_w, hlin, b2,
                                                  nullptr, colsumB, nN);

    // global features (independent, reads x)
    gfeat_kernel<<<(nN + 255) / 256, 256, 0, stream>>>(x, gs, nN);

    // head MLP
    head_kernel<<<1, 128, 0, stream>>>(colsumB, gs, Wp1, bp1, Wp2, bp2, T, Tmax, out);
}

// Round 4
// 399.105 us; speedup vs baseline: 3.7567x; 1.4094x over previous
//
#include <hip/hip_runtime.h>
#include <hip/hip_bf16.h>

#define N_NODES_C 100000
#define N_EDGES_C 1200000

// ---------------- deg: count incoming edges at dst (int) ----------------
__global__ void deg_kernel(const int* __restrict__ dst, int* __restrict__ cnt, int nE) {
    int e = blockIdx.x * blockDim.x + threadIdx.x;
    if (e < nE) atomicAdd(&cnt[dst[e]], 1);
}

// ---------------- bsum: per-1024-chunk sums of cnt ----------------
__global__ void bsum_kernel(const int* __restrict__ cnt, int* __restrict__ bsum, int nN) {
    __shared__ int sm[256];
    int tid = threadIdx.x;
    int base = blockIdx.x * 1024 + tid * 4;
    int s = 0;
#pragma unroll
    for (int k = 0; k < 4; ++k)
        if (base + k < nN) s += cnt[base + k];
    sm[tid] = s;
    __syncthreads();
    for (int off = 128; off > 0; off >>= 1) {
        if (tid < off) sm[tid] += sm[tid + off];
        __syncthreads();
    }
    if (tid == 0) bsum[blockIdx.x] = sm[0];
}

// ---------------- bscan: exclusive scan of block sums (nb <= 128) ----------------
__global__ void bscan_kernel(const int* __restrict__ bsum, int* __restrict__ boff, int nb) {
    __shared__ int sm[128];
    int tid = threadIdx.x;
    sm[tid] = (tid < nb) ? bsum[tid] : 0;
    __syncthreads();
    for (int off = 1; off < 128; off <<= 1) {
        int t = (tid >= off) ? sm[tid - off] : 0;
        __syncthreads();
        sm[tid] += t;
        __syncthreads();
    }
    if (tid < nb) boff[tid] = (tid ? sm[tid - 1] : 0);
}

// ---------------- scan_block: exclusive scan within 1024-chunk + boff -> rowptr ----------------
__global__ void scan_block_kernel(const int* __restrict__ cnt, const int* __restrict__ boff,
                                  int* __restrict__ rowptr, int nN) {
    __shared__ int sm[256];
    int tid = threadIdx.x;
    int base = blockIdx.x * 1024 + tid * 4;
    int v0 = 0, v1 = 0, v2 = 0, v3 = 0;
    if (base + 0 < nN) v0 = cnt[base + 0];
    if (base + 1 < nN) v1 = cnt[base + 1];
    if (base + 2 < nN) v2 = cnt[base + 2];
    if (base + 3 < nN) v3 = cnt[base + 3];
    int tsum = v0 + v1 + v2 + v3;
    sm[tid] = tsum;
    __syncthreads();
    for (int off = 1; off < 256; off <<= 1) {
        int t = (tid >= off) ? sm[tid - off] : 0;
        __syncthreads();
        sm[tid] += t;
        __syncthreads();
    }
    int excl = (tid ? sm[tid - 1] : 0) + boff[blockIdx.x];
    if (base + 0 <= nN) rowptr[base + 0] = excl;
    if (base + 1 <= nN) rowptr[base + 1] = excl + v0;
    if (base + 2 <= nN) rowptr[base + 2] = excl + v0 + v1;
    if (base + 3 <= nN) rowptr[base + 3] = excl + v0 + v1 + v2;
}

// ---------------- prep: dis[i] = rsqrt(cnt[i]+1) ----------------
__global__ void prep_kernel(const int* __restrict__ cnt, float* __restrict__ dis, int nN) {
    int i = blockIdx.x * 256 + threadIdx.x;
    if (i < nN) dis[i] = rsqrtf((float)(cnt[i] + 1));
}

// ---------------- bin: scatter edges into CSR slots with precomputed weights ----------------
__global__ void bin_kernel(const int* __restrict__ src, const int* __restrict__ dst,
                           const float* __restrict__ dis, const int* __restrict__ rowptr,
                           int* __restrict__ fill, int* __restrict__ csr_src,
                           float* __restrict__ csr_w, int nE) {
    int e = blockIdx.x * 256 + threadIdx.x;
    if (e < nE) {
        int s = src[e];
        int d = dst[e];
        int slot = rowptr[d] + atomicAdd(&fill[d], 1);
        csr_src[slot] = s;
        csr_w[slot] = dis[s] * dis[d];
    }
}

// ---------------- lin1: hlin = x @ W1  (x:[N,5], W1:[5,64]), grid-stride ----------------
__global__ void lin1_kernel(const float* __restrict__ x, const float* __restrict__ W1,
                            float* __restrict__ hlin, int nN) {
    __shared__ float Ws[320];
    int tid = threadIdx.x;
    if (tid < 256) Ws[tid] = W1[tid];
    if (tid < 64)  Ws[256 + tid] = W1[256 + tid];
    __syncthreads();
    int n = tid >> 6;
    int j = tid & 63;
    for (int node = blockIdx.x * 4 + n; node < nN; node += gridDim.x * 4) {
        const float* xr = x + node * 5;
        float acc = xr[0] * Ws[j]
                  + xr[1] * Ws[64 + j]
                  + xr[2] * Ws[128 + j]
                  + xr[3] * Ws[192 + j]
                  + xr[4] * Ws[256 + j];
        hlin[node * 64 + j] = acc;
    }
}

// ---------------- gather: per dst node pull; float2 lanes, even/odd edge halves ----------------
// COLSUM=false: write hout. COLSUM=true: accumulate striped column sums.
template <bool COLSUM>
__global__ void gather_kernel(const int* __restrict__ rowptr, const int* __restrict__ csr_src,
                              const float* __restrict__ csr_w, const float* __restrict__ hlin,
                              const float* __restrict__ b, float* __restrict__ hout,
                              float* __restrict__ colsum, int nN) {
    int tid = threadIdx.x;
    int lane = tid & 63;
    int wv = tid >> 6;          // wave 0..3
    int l = lane & 31;          // feature pair: features 2l, 2l+1
    int par = lane >> 5;        // 0 = even edges, 1 = odd edges
    const float2* hlin2 = (const float2*)hlin;
    float bx = b[2 * l], by = b[2 * l + 1];
    float cax = 0.0f, cay = 0.0f;
    for (int node = blockIdx.x * 4 + wv; node < nN; node += gridDim.x * 4) {
        int e0 = rowptr[node];
        int e1 = rowptr[node + 1];
        float ax = 0.0f, ay = 0.0f;
        for (int e = e0 + par; e < e1; e += 2) {
            int s = csr_src[e];
            float w = csr_w[e];
            float2 hv = hlin2[s * 32 + l];
            ax = fmaf(w, hv.x, ax);
            ay = fmaf(w, hv.y, ay);
        }
        // combine even/odd halves: lane l += lane l+32
        ax += __shfl_down(ax, 32);
        ay += __shfl_down(ay, 32);
        if (par == 0) {
            float invd = 1.0f / (float)(e1 - e0 + 1);
            float2 hs = hlin2[node * 32 + l];
            float vx = fmaxf(ax + hs.x * invd + bx, 0.0f);
            float vy = fmaxf(ay + hs.y * invd + by, 0.0f);
            if (COLSUM) { cax += vx; cay += vy; }
            else {
                float2 v; v.x = vx; v.y = vy;
                ((float2*)hout)[node * 32 + l] = v;
            }
        }
    }
    if (COLSUM) {
        __shared__ float smx[4][32], smy[4][32];
        if (par == 0) { smx[wv][l] = cax; smy[wv][l] = cay; }
        __syncthreads();
        if (tid < 32) {
            float sx = smx[0][tid] + smx[1][tid] + smx[2][tid] + smx[3][tid];
            float sy = smy[0][tid] + smy[1][tid] + smy[2][tid] + smy[3][tid];
            int bank = blockIdx.x & 15;
            atomicAdd(&colsum[bank * 64 + 2 * tid], sx);
            atomicAdd(&colsum[bank * 64 + 2 * tid + 1], sy);
        }
    }
}

// ---------------- lin2: hlin = h1 @ W2, grid-stride, W2 staged once ----------------
__global__ void lin2_kernel(const float* __restrict__ h1, const float* __restrict__ W2,
                            float* __restrict__ hlin, int nN) {
    __shared__ float Ws[64 * 64];
    __shared__ float rows[4][64];
    int tid = threadIdx.x;
    for (int i = tid; i < 4096; i += 256) Ws[i] = W2[i];
    __syncthreads();
    int n = tid >> 6;
    int j = tid & 63;
    for (int node = blockIdx.x * 4 + n; node < nN; node += gridDim.x * 4) {
        rows[n][j] = h1[node * 64 + j];  // own-wave write; compiler inserts lgkm wait
        float acc = 0.0f;
#pragma unroll
        for (int k = 0; k < 64; ++k) acc += rows[n][k] * Ws[k * 64 + j];
        hlin[node * 64 + j] = acc;
    }
}

// ---------------- gfeat: block-reduced column sums, striped atomic banks ----------------
// gsB[bank*16+k]: k: 0=sum x0*m, 1=sum x1*m, 2=sum x2, 3=sum x3, 4=sum x4, 5=msum
__global__ void gfeat_kernel(const float* __restrict__ x, float* __restrict__ gsB, int nN) {
    int tid = threadIdx.x;
    int i = blockIdx.x * 256 + tid;
    float s0 = 0, s1 = 0, s2 = 0, s3 = 0, s4 = 0, s5 = 0;
    if (i < nN) {
        const float* xr = x + i * 5;
        float x0 = xr[0], x1 = xr[1], x2 = xr[2], x3 = xr[3], x4 = xr[4];
        float m = (x2 == 1.0f) ? 1.0f : 0.0f;
        s0 = x0 * m; s1 = x1 * m; s2 = x2; s3 = x3; s4 = x4; s5 = m;
    }
#pragma unroll
    for (int off = 32; off > 0; off >>= 1) {
        s0 += __shfl_down(s0, off);
        s1 += __shfl_down(s1, off);
        s2 += __shfl_down(s2, off);
        s3 += __shfl_down(s3, off);
        s4 += __shfl_down(s4, off);
        s5 += __shfl_down(s5, off);
    }
    __shared__ float smg[4][6];
    if ((tid & 63) == 0) {
        int w = tid >> 6;
        smg[w][0] = s0; smg[w][1] = s1; smg[w][2] = s2;
        smg[w][3] = s3; smg[w][4] = s4; smg[w][5] = s5;
    }
    __syncthreads();
    if (tid < 6) {
        float s = smg[0][tid] + smg[1][tid] + smg[2][tid] + smg[3][tid];
        atomicAdd(&gsB[(blockIdx.x & 15) * 16 + tid], s);
    }
}

// ---------------- head: reduce striped sums; MLP 71->32->2 -> 2+4*sigmoid ----------------
__global__ void head_kernel(const float* __restrict__ colsumB, const float* __restrict__ gsB,
                            const float* __restrict__ Wp1, const float* __restrict__ bp1,
                            const float* __restrict__ Wp2, const float* __restrict__ bp2,
                            const int* __restrict__ T, const int* __restrict__ Tmax,
                            float* __restrict__ out) {
    __shared__ float e[71];
    __shared__ float gsum[6];
    __shared__ float hid[32];
    int tid = threadIdx.x;
    if (tid < 64) {
        float s = 0.0f;
#pragma unroll
        for (int r = 0; r < 16; ++r) s += colsumB[r * 64 + tid];
        e[tid] = s * (1.0f / (float)N_NODES_C);
    } else if (tid < 70) {
        int k = tid - 64;
        float s = 0.0f;
#pragma unroll
        for (int r = 0; r < 16; ++r) s += gsB[r * 16 + k];
        gsum[k] = s;
    }
    __syncthreads();
    if (tid == 0) {
        e[64] = gsum[2];                  // n_comp
        e[65] = gsum[3];                  // n_AND
        e[66] = gsum[4];                  // n_OR
        e[67] = gsum[3] + gsum[4];        // depth
        float m = gsum[5];
        e[68] = (m > 0.0f) ? gsum[0] / fmaxf(m, 1.0f) : 0.0f;  // avg_lambda
        e[69] = (m > 0.0f) ? gsum[1] / fmaxf(m, 1.0f) : 0.0f;  // avg_mu
        e[70] = (float)T[0] / (float)Tmax[0];                  // T_norm
    }
    __syncthreads();
    if (tid < 32) {
        float acc = bp1[tid];
        for (int i = 0; i < 71; ++i) acc += e[i] * Wp1[i * 32 + tid];
        hid[tid] = fmaxf(acc, 0.0f);
    }
    __syncthreads();
    if (tid < 2) {
        float acc = bp2[tid];
        for (int k = 0; k < 32; ++k) acc += hid[k] * Wp2[k * 2 + tid];
        out[tid] = 2.0f + 4.0f / (1.0f + expf(-acc));
    }
}

extern "C" void kernel_launch(void* const* d_in, const int* in_sizes, int n_in,
                              void* d_out, int out_size, void* d_ws, size_t ws_size,
                              hipStream_t stream) {
    const float* x    = (const float*)d_in[0];
    const int*   ei   = (const int*)d_in[1];
    const float* W1   = (const float*)d_in[2];
    const float* b1   = (const float*)d_in[3];
    const float* W2   = (const float*)d_in[4];
    const float* b2   = (const float*)d_in[5];
    const float* Wp1  = (const float*)d_in[6];
    const float* bp1  = (const float*)d_in[7];
    const float* Wp2  = (const float*)d_in[8];
    const float* bp2  = (const float*)d_in[9];
    const int*   T    = (const int*)d_in[10];
    const int*   Tmax = (const int*)d_in[11];
    float* out = (float*)d_out;

    const int nN = N_NODES_C;
    const int nE = N_EDGES_C;
    const int* src = ei;
    const int* dst = ei + nE;

    char* ws = (char*)d_ws;
    int*   cnt     = (int*)  (ws + 0);           // 400000
    int*   fill    = (int*)  (ws + 400000);      // 400000
    float* colsumB = (float*)(ws + 800000);      // 16*64*4 = 4096
    float* gsB     = (float*)(ws + 804096);      // 16*16*4 = 1024
    int*   bsum    = (int*)  (ws + 805120);      // 512
    int*   boff    = (int*)  (ws + 805632);      // 512
    int*   rowptr  = (int*)  (ws + 806144);      // 400016
    float* dis     = (float*)(ws + 1206160);     // 400000
    int*   csr_src = (int*)  (ws + 1606160);     // 4.8 MB
    float* csr_w   = (float*)(ws + 6406160);     // 4.8 MB
    float* hlin    = (float*)(ws + 11206160);    // 25.6 MB (8B aligned)
    float* h1      = (float*)(ws + 36806160);    // 25.6 MB (8B aligned)

    // zero: cnt + fill + colsumB + gsB
    hipMemsetAsync(ws, 0, 805120, stream);

    const int nb = (nN + 1023) / 1024;  // 98

    // CSR build (weights shared by both layers)
    deg_kernel<<<(nE + 255) / 256, 256, 0, stream>>>(dst, cnt, nE);
    bsum_kernel<<<nb, 256, 0, stream>>>(cnt, bsum, nN);
    bscan_kernel<<<1, 128, 0, stream>>>(bsum, boff, nb);
    scan_block_kernel<<<nb, 256, 0, stream>>>(cnt, boff, rowptr, nN);
    prep_kernel<<<(nN + 255) / 256, 256, 0, stream>>>(cnt, dis, nN);
    bin_kernel<<<(nE + 255) / 256, 256, 0, stream>>>(src, dst, dis, rowptr, fill,
                                                     csr_src, csr_w, nE);

    // layer 1: lin + pull-gather (fused self-loop+bias+relu)
    lin1_kernel<<<1024, 256, 0, stream>>>(x, W1, hlin, nN);
    gather_kernel<false><<<2048, 256, 0, stream>>>(rowptr, csr_src, csr_w, hlin, b1,
                                                   h1, nullptr, nN);

    // layer 2: lin + pull-gather fused with column-sum (mean pool)
    lin2_kernel<<<1024, 256, 0, stream>>>(h1, W2, hlin, nN);
    gather_kernel<true><<<2048, 256, 0, stream>>>(rowptr, csr_src, csr_w, hlin, b2,
                                                  nullptr, colsumB, nN);

    // global features (independent, reads x)
    gfeat_kernel<<<(nN + 255) / 256, 256, 0, stream>>>(x, gsB, nN);

    // head MLP
    head_kernel<<<1, 128, 0, stream>>>(colsumB, gsB, Wp1, bp1, Wp2, bp2, T, Tmax, out);
}

// Round 5
// 313.647 us; speedup vs baseline: 4.7803x; 1.2725x over previous
//
#include <hip/hip_runtime.h>
#include <hip/hip_bf16.h>

#define N_NODES_C 100000
#define N_EDGES_C 1200000

typedef unsigned int uint32;
typedef __attribute__((ext_vector_type(8))) short bf16x8;
typedef __attribute__((ext_vector_type(4))) float f32x4;

__device__ __forceinline__ float bfasf(uint32 hi_bits) { return __uint_as_float(hi_bits); }
__device__ __forceinline__ float bf_lo(uint32 u) { return __uint_as_float(u << 16); }
__device__ __forceinline__ float bf_hi(uint32 u) { return __uint_as_float(u & 0xffff0000u); }
__device__ __forceinline__ uint32 bf16r(float f) {  // RNE f32 -> bf16 (low 16 bits)
    uint32 u = __float_as_uint(f);
    return (u + 0x7fffu + ((u >> 16) & 1u)) >> 16;
}
__device__ __forceinline__ uint32 pack2(float lo, float hi) {
    return bf16r(lo) | (bf16r(hi) << 16);
}

// ---------------- deg: count incoming edges at dst (int) ----------------
__global__ void deg_kernel(const int* __restrict__ dst, int* __restrict__ cnt, int nE) {
    int e = blockIdx.x * blockDim.x + threadIdx.x;
    if (e < nE) atomicAdd(&cnt[dst[e]], 1);
}

// ---------------- bsum: per-1024-chunk sums of cnt ----------------
__global__ void bsum_kernel(const int* __restrict__ cnt, int* __restrict__ bsum, int nN) {
    __shared__ int sm[256];
    int tid = threadIdx.x;
    int base = blockIdx.x * 1024 + tid * 4;
    int s = 0;
#pragma unroll
    for (int k = 0; k < 4; ++k)
        if (base + k < nN) s += cnt[base + k];
    sm[tid] = s;
    __syncthreads();
    for (int off = 128; off > 0; off >>= 1) {
        if (tid < off) sm[tid] += sm[tid + off];
        __syncthreads();
    }
    if (tid == 0) bsum[blockIdx.x] = sm[0];
}

// ---------------- bscan: exclusive scan of block sums (nb <= 128) ----------------
__global__ void bscan_kernel(const int* __restrict__ bsum, int* __restrict__ boff, int nb) {
    __shared__ int sm[128];
    int tid = threadIdx.x;
    sm[tid] = (tid < nb) ? bsum[tid] : 0;
    __syncthreads();
    for (int off = 1; off < 128; off <<= 1) {
        int t = (tid >= off) ? sm[tid - off] : 0;
        __syncthreads();
        sm[tid] += t;
        __syncthreads();
    }
    if (tid < nb) boff[tid] = (tid ? sm[tid - 1] : 0);
}

// ---------------- scan_block: exclusive scan within 1024-chunk + boff -> rowptr ----------------
__global__ void scan_block_kernel(const int* __restrict__ cnt, const int* __restrict__ boff,
                                  int* __restrict__ rowptr, int nN) {
    __shared__ int sm[256];
    int tid = threadIdx.x;
    int base = blockIdx.x * 1024 + tid * 4;
    int v0 = 0, v1 = 0, v2 = 0, v3 = 0;
    if (base + 0 < nN) v0 = cnt[base + 0];
    if (base + 1 < nN) v1 = cnt[base + 1];
    if (base + 2 < nN) v2 = cnt[base + 2];
    if (base + 3 < nN) v3 = cnt[base + 3];
    int tsum = v0 + v1 + v2 + v3;
    sm[tid] = tsum;
    __syncthreads();
    for (int off = 1; off < 256; off <<= 1) {
        int t = (tid >= off) ? sm[tid - off] : 0;
        __syncthreads();
        sm[tid] += t;
        __syncthreads();
    }
    int excl = (tid ? sm[tid - 1] : 0) + boff[blockIdx.x];
    if (base + 0 <= nN) rowptr[base + 0] = excl;
    if (base + 1 <= nN) rowptr[base + 1] = excl + v0;
    if (base + 2 <= nN) rowptr[base + 2] = excl + v0 + v1;
    if (base + 3 <= nN) rowptr[base + 3] = excl + v0 + v1 + v2;
}

// ---------------- prep: dis[i] = rsqrt(cnt[i]+1) ----------------
__global__ void prep_kernel(const int* __restrict__ cnt, float* __restrict__ dis, int nN) {
    int i = blockIdx.x * 256 + threadIdx.x;
    if (i < nN) dis[i] = rsqrtf((float)(cnt[i] + 1));
}

// ---------------- bin: scatter edges into CSR slots, interleaved {src, w} ----------------
__global__ void bin_kernel(const int* __restrict__ src, const int* __restrict__ dst,
                           const float* __restrict__ dis, const int* __restrict__ rowptr,
                           int* __restrict__ fill, int2* __restrict__ csr, int nE) {
    int e = blockIdx.x * 256 + threadIdx.x;
    if (e < nE) {
        int s = src[e];
        int d = dst[e];
        int slot = rowptr[d] + atomicAdd(&fill[d], 1);
        float w = dis[s] * dis[d];
        csr[slot] = make_int2(s, __float_as_int(w));
    }
}

// ---------------- lin1: hlin = x @ W1 -> bf16 rows [N][64] ----------------
__global__ void lin1_kernel(const float* __restrict__ x, const float* __restrict__ W1,
                            uint32* __restrict__ hlin, int nN) {
    __shared__ float Ws[320];
    int tid = threadIdx.x;
    if (tid < 256) Ws[tid] = W1[tid];
    if (tid < 64)  Ws[256 + tid] = W1[256 + tid];
    __syncthreads();
    int l = tid & 31;     // feature pair 2l, 2l+1
    int sub = tid >> 5;   // 8 nodes per block pass
    for (int node = blockIdx.x * 8 + sub; node < nN; node += gridDim.x * 8) {
        const float* xr = x + node * 5;
        float x0 = xr[0], x1 = xr[1], x2 = xr[2], x3 = xr[3], x4 = xr[4];
        int j0 = 2 * l, j1 = 2 * l + 1;
        float a = x0 * Ws[j0] + x1 * Ws[64 + j0] + x2 * Ws[128 + j0]
                + x3 * Ws[192 + j0] + x4 * Ws[256 + j0];
        float b = x0 * Ws[j1] + x1 * Ws[64 + j1] + x2 * Ws[128 + j1]
                + x3 * Ws[192 + j1] + x4 * Ws[256 + j1];
        hlin[node * 32 + l] = pack2(a, b);
    }
}

// ---------------- gather: z[dst] = sum w*h[src] + h[dst]*invd  (bf16 in/out) ----------------
// Wave per node: lane = (par 0..3, l 0..15); lane handles features 4l..4l+3; 4-way edge ILP.
// EPI: apply +bias, relu (layer 1). Otherwise raw z (layer 2 pre-GEMM).
template <bool EPI>
__global__ void gather_kernel(const int* __restrict__ rowptr, const int2* __restrict__ csr,
                              const uint2* __restrict__ hin, const float* __restrict__ bias,
                              uint2* __restrict__ hout, int nN) {
    int tid = threadIdx.x;
    int lane = tid & 63;
    int wv = tid >> 6;
    int l = lane & 15;
    int par = lane >> 4;
    float b0 = 0, b1 = 0, b2 = 0, b3 = 0;
    if (EPI) { b0 = bias[4 * l]; b1 = bias[4 * l + 1]; b2 = bias[4 * l + 2]; b3 = bias[4 * l + 3]; }
    for (int node = blockIdx.x * 4 + wv; node < nN; node += gridDim.x * 4) {
        int e0 = rowptr[node];
        int e1 = rowptr[node + 1];
        float a0 = 0, a1 = 0, a2 = 0, a3 = 0;
        for (int e = e0 + par; e < e1; e += 4) {
            int2 m = csr[e];
            float w = __int_as_float(m.y);
            uint2 hv = hin[m.x * 16 + l];
            a0 = fmaf(w, bf_lo(hv.x), a0);
            a1 = fmaf(w, bf_hi(hv.x), a1);
            a2 = fmaf(w, bf_lo(hv.y), a2);
            a3 = fmaf(w, bf_hi(hv.y), a3);
        }
        a0 += __shfl_down(a0, 32); a1 += __shfl_down(a1, 32);
        a2 += __shfl_down(a2, 32); a3 += __shfl_down(a3, 32);
        a0 += __shfl_down(a0, 16); a1 += __shfl_down(a1, 16);
        a2 += __shfl_down(a2, 16); a3 += __shfl_down(a3, 16);
        if (par == 0) {
            float invd = 1.0f / (float)(e1 - e0 + 1);
            uint2 hs = hin[node * 16 + l];
            float v0 = a0 + bf_lo(hs.x) * invd;
            float v1 = a1 + bf_hi(hs.x) * invd;
            float v2 = a2 + bf_lo(hs.y) * invd;
            float v3 = a3 + bf_hi(hs.y) * invd;
            if (EPI) {
                v0 = fmaxf(v0 + b0, 0.0f); v1 = fmaxf(v1 + b1, 0.0f);
                v2 = fmaxf(v2 + b2, 0.0f); v3 = fmaxf(v3 + b3, 0.0f);
            }
            hout[node * 16 + l] = make_uint2(pack2(v0, v1), pack2(v2, v3));
        }
    }
}

// ---------------- lin2pool: colsum += relu(z2 @ W2 + b2) via MFMA, no store of h2 ----------------
// Tile = 16 nodes. A: z2 rows (bf16). B: W2 cast to bf16. C layout (m89): col=lane&15, row=(lane>>4)*4+reg.
__global__ void lin2pool_kernel(const uint2* __restrict__ z2, const float* __restrict__ W2,
                                const float* __restrict__ b2, float* __restrict__ colsumB,
                                int nTiles) {
    int tid = threadIdx.x;
    int lane = tid & 63;
    int wv = tid >> 6;
    int l16 = lane & 15;
    int kg = lane >> 4;  // 0..3

    // B fragments: 2 k-steps x 4 j-tiles; lane holds B[k = ks*32+kg*8+r][j = t*16+l16]
    bf16x8 Bf[2][4];
#pragma unroll
    for (int ks = 0; ks < 2; ++ks)
#pragma unroll
        for (int t = 0; t < 4; ++t) {
            bf16x8 bb;
#pragma unroll
            for (int r = 0; r < 8; ++r) {
                int k = ks * 32 + kg * 8 + r;
                bb[r] = (short)bf16r(W2[k * 64 + t * 16 + l16]);
            }
            Bf[ks][t] = bb;
        }
    float bbias[4];
#pragma unroll
    for (int t = 0; t < 4; ++t) bbias[t] = b2[t * 16 + l16];

    float colacc[4][4];
#pragma unroll
    for (int t = 0; t < 4; ++t)
#pragma unroll
        for (int r = 0; r < 4; ++r) colacc[t][r] = 0.0f;

    for (int tile = blockIdx.x * 4 + wv; tile < nTiles; tile += gridDim.x * 4) {
        int nodeBase = tile * 16;
        // A frags: lane holds A[row=l16][k=kg*8+0..7] (+32 for k-step 1); 16B per load
        const uint4* zrow = (const uint4*)(z2 + (size_t)(nodeBase + l16) * 16);
        uint4 A0u = zrow[kg];
        uint4 A1u = zrow[4 + kg];
        union { uint4 u; bf16x8 b; } c0, c1;
        c0.u = A0u; c1.u = A1u;
        f32x4 acc0 = {0, 0, 0, 0}, acc1 = {0, 0, 0, 0}, acc2 = {0, 0, 0, 0}, acc3 = {0, 0, 0, 0};
        acc0 = __builtin_amdgcn_mfma_f32_16x16x32_bf16(c0.b, Bf[0][0], acc0, 0, 0, 0);
        acc1 = __builtin_amdgcn_mfma_f32_16x16x32_bf16(c0.b, Bf[0][1], acc1, 0, 0, 0);
        acc2 = __builtin_amdgcn_mfma_f32_16x16x32_bf16(c0.b, Bf[0][2], acc2, 0, 0, 0);
        acc3 = __builtin_amdgcn_mfma_f32_16x16x32_bf16(c0.b, Bf[0][3], acc3, 0, 0, 0);
        acc0 = __builtin_amdgcn_mfma_f32_16x16x32_bf16(c1.b, Bf[1][0], acc0, 0, 0, 0);
        acc1 = __builtin_amdgcn_mfma_f32_16x16x32_bf16(c1.b, Bf[1][1], acc1, 0, 0, 0);
        acc2 = __builtin_amdgcn_mfma_f32_16x16x32_bf16(c1.b, Bf[1][2], acc2, 0, 0, 0);
        acc3 = __builtin_amdgcn_mfma_f32_16x16x32_bf16(c1.b, Bf[1][3], acc3, 0, 0, 0);
#pragma unroll
        for (int r = 0; r < 4; ++r) {
            colacc[0][r] += fmaxf(acc0[r] + bbias[0], 0.0f);
            colacc[1][r] += fmaxf(acc1[r] + bbias[1], 0.0f);
            colacc[2][r] += fmaxf(acc2[r] + bbias[2], 0.0f);
            colacc[3][r] += fmaxf(acc3[r] + bbias[3], 0.0f);
        }
    }
    // reduce: sum regs (nodes), then lanes 16/32 apart (nodes), leaving per-j partials
    float s[4];
#pragma unroll
    for (int t = 0; t < 4; ++t) {
        s[t] = colacc[t][0] + colacc[t][1] + colacc[t][2] + colacc[t][3];
        s[t] += __shfl_down(s[t], 32);
        s[t] += __shfl_down(s[t], 16);
    }
    __shared__ float sm[4][64];
    if (lane < 16) {
#pragma unroll
        for (int t = 0; t < 4; ++t) sm[wv][t * 16 + lane] = s[t];
    }
    __syncthreads();
    if (tid < 64) {
        float v = sm[0][tid] + sm[1][tid] + sm[2][tid] + sm[3][tid];
        atomicAdd(&colsumB[(blockIdx.x & 15) * 64 + tid], v);
    }
}

// ---------------- gfeat: block-reduced column sums, striped atomic banks ----------------
__global__ void gfeat_kernel(const float* __restrict__ x, float* __restrict__ gsB, int nN) {
    int tid = threadIdx.x;
    int i = blockIdx.x * 256 + tid;
    float s0 = 0, s1 = 0, s2 = 0, s3 = 0, s4 = 0, s5 = 0;
    if (i < nN) {
        const float* xr = x + i * 5;
        float x0 = xr[0], x1 = xr[1], x2 = xr[2], x3 = xr[3], x4 = xr[4];
        float m = (x2 == 1.0f) ? 1.0f : 0.0f;
        s0 = x0 * m; s1 = x1 * m; s2 = x2; s3 = x3; s4 = x4; s5 = m;
    }
#pragma unroll
    for (int off = 32; off > 0; off >>= 1) {
        s0 += __shfl_down(s0, off);
        s1 += __shfl_down(s1, off);
        s2 += __shfl_down(s2, off);
        s3 += __shfl_down(s3, off);
        s4 += __shfl_down(s4, off);
        s5 += __shfl_down(s5, off);
    }
    __shared__ float smg[4][6];
    if ((tid & 63) == 0) {
        int w = tid >> 6;
        smg[w][0] = s0; smg[w][1] = s1; smg[w][2] = s2;
        smg[w][3] = s3; smg[w][4] = s4; smg[w][5] = s5;
    }
    __syncthreads();
    if (tid < 6) {
        float s = smg[0][tid] + smg[1][tid] + smg[2][tid] + smg[3][tid];
        atomicAdd(&gsB[(blockIdx.x & 15) * 16 + tid], s);
    }
}

// ---------------- head: reduce striped sums; MLP 71->32->2 -> 2+4*sigmoid ----------------
__global__ void head_kernel(const float* __restrict__ colsumB, const float* __restrict__ gsB,
                            const float* __restrict__ Wp1, const float* __restrict__ bp1,
                            const float* __restrict__ Wp2, const float* __restrict__ bp2,
                            const int* __restrict__ T, const int* __restrict__ Tmax,
                            float* __restrict__ out) {
    __shared__ float e[71];
    __shared__ float gsum[6];
    __shared__ float hid[32];
    int tid = threadIdx.x;
    if (tid < 64) {
        float s = 0.0f;
#pragma unroll
        for (int r = 0; r < 16; ++r) s += colsumB[r * 64 + tid];
        e[tid] = s * (1.0f / (float)N_NODES_C);
    } else if (tid < 70) {
        int k = tid - 64;
        float s = 0.0f;
#pragma unroll
        for (int r = 0; r < 16; ++r) s += gsB[r * 16 + k];
        gsum[k] = s;
    }
    __syncthreads();
    if (tid == 0) {
        e[64] = gsum[2];
        e[65] = gsum[3];
        e[66] = gsum[4];
        e[67] = gsum[3] + gsum[4];
        float m = gsum[5];
        e[68] = (m > 0.0f) ? gsum[0] / fmaxf(m, 1.0f) : 0.0f;
        e[69] = (m > 0.0f) ? gsum[1] / fmaxf(m, 1.0f) : 0.0f;
        e[70] = (float)T[0] / (float)Tmax[0];
    }
    __syncthreads();
    if (tid < 32) {
        float acc = bp1[tid];
        for (int i = 0; i < 71; ++i) acc += e[i] * Wp1[i * 32 + tid];
        hid[tid] = fmaxf(acc, 0.0f);
    }
    __syncthreads();
    if (tid < 2) {
        float acc = bp2[tid];
        for (int k = 0; k < 32; ++k) acc += hid[k] * Wp2[k * 2 + tid];
        out[tid] = 2.0f + 4.0f / (1.0f + expf(-acc));
    }
}

extern "C" void kernel_launch(void* const* d_in, const int* in_sizes, int n_in,
                              void* d_out, int out_size, void* d_ws, size_t ws_size,
                              hipStream_t stream) {
    const float* x    = (const float*)d_in[0];
    const int*   ei   = (const int*)d_in[1];
    const float* W1   = (const float*)d_in[2];
    const float* b1   = (const float*)d_in[3];
    const float* W2   = (const float*)d_in[4];
    const float* b2   = (const float*)d_in[5];
    const float* Wp1  = (const float*)d_in[6];
    const float* bp1  = (const float*)d_in[7];
    const float* Wp2  = (const float*)d_in[8];
    const float* bp2  = (const float*)d_in[9];
    const int*   T    = (const int*)d_in[10];
    const int*   Tmax = (const int*)d_in[11];
    float* out = (float*)d_out;

    const int nN = N_NODES_C;
    const int nE = N_EDGES_C;
    const int* src = ei;
    const int* dst = ei + nE;

    char* ws = (char*)d_ws;
    int*    cnt     = (int*)   (ws + 0);           // 400000
    int*    fill    = (int*)   (ws + 400000);      // 400000
    float*  colsumB = (float*) (ws + 800000);      // 16*64*4 = 4096
    float*  gsB     = (float*) (ws + 804096);      // 16*16*4 = 1024
    int*    bsum    = (int*)   (ws + 805120);      // 512
    int*    boff    = (int*)   (ws + 805632);      // 512
    int*    rowptr  = (int*)   (ws + 806144);      // 400016 (pad to 1206160)
    float*  dis     = (float*) (ws + 1206160);     // 400000
    int2*   csr     = (int2*)  (ws + 1606160);     // 9.6 MB interleaved {src, w}
    uint32* hlin1   = (uint32*)(ws + 11206160);    // 12.8 MB bf16 [N][64]
    uint32* h1      = (uint32*)(ws + 24006160);    // 12.8 MB bf16
    uint32* z2      = (uint32*)(ws + 36806160);    // 12.8 MB bf16

    hipMemsetAsync(ws, 0, 805120, stream);  // cnt + fill + colsumB + gsB

    const int nb = (nN + 1023) / 1024;  // 98

    // CSR build (weights shared by both layers)
    deg_kernel<<<(nE + 255) / 256, 256, 0, stream>>>(dst, cnt, nE);
    bsum_kernel<<<nb, 256, 0, stream>>>(cnt, bsum, nN);
    bscan_kernel<<<1, 128, 0, stream>>>(bsum, boff, nb);
    scan_block_kernel<<<nb, 256, 0, stream>>>(cnt, boff, rowptr, nN);
    prep_kernel<<<(nN + 255) / 256, 256, 0, stream>>>(cnt, dis, nN);
    bin_kernel<<<(nE + 255) / 256, 256, 0, stream>>>(src, dst, dis, rowptr, fill, csr, nE);

    // layer 1: lin1 (bf16 out) + gather (+b1, relu) -> h1 bf16
    lin1_kernel<<<1024, 256, 0, stream>>>(x, W1, hlin1, nN);
    gather_kernel<true><<<2048, 256, 0, stream>>>(rowptr, csr, (const uint2*)hlin1, b1,
                                                  (uint2*)h1, nN);

    // layer 2: gather raw z2 = agg(h1); then relu(z2@W2+b2) pooled via MFMA
    gather_kernel<false><<<2048, 256, 0, stream>>>(rowptr, csr, (const uint2*)h1, nullptr,
                                                   (uint2*)z2, nN);
    lin2pool_kernel<<<512, 256, 0, stream>>>((const uint2*)z2, W2, b2, colsumB, nN / 16);

    // global features (independent, reads x)
    gfeat_kernel<<<(nN + 255) / 256, 256, 0, stream>>>(x, gsB, nN);

    // head MLP
    head_kernel<<<1, 128, 0, stream>>>(colsumB, gsB, Wp1, bp1, Wp2, bp2, T, Tmax, out);
}

// Round 6
// 307.909 us; speedup vs baseline: 4.8694x; 1.0186x over previous
//
#include <hip/hip_runtime.h>
#include <hip/hip_bf16.h>

#define N_NODES_C 100000
#define N_EDGES_C 1200000

typedef unsigned int uint32;
typedef __attribute__((ext_vector_type(8))) short bf16x8;
typedef __attribute__((ext_vector_type(4))) float f32x4;

__device__ __forceinline__ float bf_lo(uint32 u) { return __uint_as_float(u << 16); }
__device__ __forceinline__ float bf_hi(uint32 u) { return __uint_as_float(u & 0xffff0000u); }
__device__ __forceinline__ uint32 bf16r(float f) {  // RNE f32 -> bf16 (low 16 bits)
    uint32 u = __float_as_uint(f);
    return (u + 0x7fffu + ((u >> 16) & 1u)) >> 16;
}
__device__ __forceinline__ uint32 pack2(float lo, float hi) {
    return bf16r(lo) | (bf16r(hi) << 16);
}

// ---------------- deg: count incoming edges at dst (int4 loads) ----------------
__global__ void deg_kernel(const int4* __restrict__ dst4, int* __restrict__ cnt, int nE4) {
    int i = blockIdx.x * blockDim.x + threadIdx.x;
    if (i < nE4) {
        int4 v = dst4[i];
        atomicAdd(&cnt[v.x], 1);
        atomicAdd(&cnt[v.y], 1);
        atomicAdd(&cnt[v.z], 1);
        atomicAdd(&cnt[v.w], 1);
    }
}

// ---------------- bsum: per-1024-chunk sums of cnt ----------------
__global__ void bsum_kernel(const int* __restrict__ cnt, int* __restrict__ bsum, int nN) {
    __shared__ int sm[256];
    int tid = threadIdx.x;
    int base = blockIdx.x * 1024 + tid * 4;
    int s = 0;
#pragma unroll
    for (int k = 0; k < 4; ++k)
        if (base + k < nN) s += cnt[base + k];
    sm[tid] = s;
    __syncthreads();
    for (int off = 128; off > 0; off >>= 1) {
        if (tid < off) sm[tid] += sm[tid + off];
        __syncthreads();
    }
    if (tid == 0) bsum[blockIdx.x] = sm[0];
}

// ---------------- bscan: exclusive scan of block sums (nb <= 128) ----------------
__global__ void bscan_kernel(const int* __restrict__ bsum, int* __restrict__ boff, int nb) {
    __shared__ int sm[128];
    int tid = threadIdx.x;
    sm[tid] = (tid < nb) ? bsum[tid] : 0;
    __syncthreads();
    for (int off = 1; off < 128; off <<= 1) {
        int t = (tid >= off) ? sm[tid - off] : 0;
        __syncthreads();
        sm[tid] += t;
        __syncthreads();
    }
    if (tid < nb) boff[tid] = (tid ? sm[tid - 1] : 0);
}

// ---------------- scan_block: rowptr (exclusive scan) + dis = rsqrt(cnt+1) fused ----------------
__global__ void scan_block_kernel(const int* __restrict__ cnt, const int* __restrict__ boff,
                                  int* __restrict__ rowptr, float* __restrict__ dis, int nN) {
    __shared__ int sm[256];
    int tid = threadIdx.x;
    int base = blockIdx.x * 1024 + tid * 4;
    int v0 = 0, v1 = 0, v2 = 0, v3 = 0;
    if (base + 0 < nN) v0 = cnt[base + 0];
    if (base + 1 < nN) v1 = cnt[base + 1];
    if (base + 2 < nN) v2 = cnt[base + 2];
    if (base + 3 < nN) v3 = cnt[base + 3];
    int tsum = v0 + v1 + v2 + v3;
    sm[tid] = tsum;
    __syncthreads();
    for (int off = 1; off < 256; off <<= 1) {
        int t = (tid >= off) ? sm[tid - off] : 0;
        __syncthreads();
        sm[tid] += t;
        __syncthreads();
    }
    int excl = (tid ? sm[tid - 1] : 0) + boff[blockIdx.x];
    if (base + 0 <= nN) rowptr[base + 0] = excl;
    if (base + 1 <= nN) rowptr[base + 1] = excl + v0;
    if (base + 2 <= nN) rowptr[base + 2] = excl + v0 + v1;
    if (base + 3 <= nN) rowptr[base + 3] = excl + v0 + v1 + v2;
    if (base + 0 < nN) dis[base + 0] = rsqrtf((float)(v0 + 1));
    if (base + 1 < nN) dis[base + 1] = rsqrtf((float)(v1 + 1));
    if (base + 2 < nN) dis[base + 2] = rsqrtf((float)(v2 + 1));
    if (base + 3 < nN) dis[base + 3] = rsqrtf((float)(v3 + 1));
}

// ---------------- bin: scatter edge src into CSR slot (4B entries, no weight) ----------------
__global__ void bin_kernel(const int* __restrict__ src, const int* __restrict__ dst,
                           const int* __restrict__ rowptr, int* __restrict__ fill,
                           int* __restrict__ csr_src, int nE) {
    int e = blockIdx.x * 256 + threadIdx.x;
    if (e < nE) {
        int s = src[e];
        int d = dst[e];
        int slot = rowptr[d] + atomicAdd(&fill[d], 1);
        csr_src[slot] = s;
    }
}

// ---------------- lin1: hlin1' = dis * (x @ W1) -> bf16 rows [N][64] ----------------
__global__ void lin1_kernel(const float* __restrict__ x, const float* __restrict__ W1,
                            const float* __restrict__ dis, uint32* __restrict__ hlin, int nN) {
    __shared__ float Ws[320];
    int tid = threadIdx.x;
    if (tid < 256) Ws[tid] = W1[tid];
    if (tid < 64)  Ws[256 + tid] = W1[256 + tid];
    __syncthreads();
    int l = tid & 31;     // feature pair 2l, 2l+1
    int sub = tid >> 5;   // 8 nodes per block pass
    for (int node = blockIdx.x * 8 + sub; node < nN; node += gridDim.x * 8) {
        const float* xr = x + node * 5;
        float x0 = xr[0], x1 = xr[1], x2 = xr[2], x3 = xr[3], x4 = xr[4];
        float dn = dis[node];
        int j0 = 2 * l, j1 = 2 * l + 1;
        float a = x0 * Ws[j0] + x1 * Ws[64 + j0] + x2 * Ws[128 + j0]
                + x3 * Ws[192 + j0] + x4 * Ws[256 + j0];
        float b = x0 * Ws[j1] + x1 * Ws[64 + j1] + x2 * Ws[128 + j1]
                + x3 * Ws[192 + j1] + x4 * Ws[256 + j1];
        hlin[node * 32 + l] = pack2(a * dn, b * dn);
    }
}

// ---------------- gather: unweighted pull of pre-scaled rows ----------------
// Wave per node: lane = (par 0..7, l 0..7); lane covers features 8l..8l+7 (16B); 8-way edge ILP.
// acc = sum_{s in N(d)} h'[s] + h'[d];  EPI (layer1): out = dis*relu(dis*acc + b)  [pre-scaled h1']
//                                      !EPI (layer2): out = dis*acc               [z2' for GEMM]
template <bool EPI>
__global__ void gather_kernel(const int* __restrict__ rowptr, const int* __restrict__ csr_src,
                              const uint4* __restrict__ hin, const float* __restrict__ bias,
                              uint4* __restrict__ hout, int nN) {
    int tid = threadIdx.x;
    int lane = tid & 63;
    int wv = tid >> 6;
    int l = lane & 7;        // feature octet
    int par = lane >> 3;     // 0..7 edge slice
    float bb0 = 0, bb1 = 0, bb2 = 0, bb3 = 0, bb4 = 0, bb5 = 0, bb6 = 0, bb7 = 0;
    if (EPI) {
        const float* bp = bias + 8 * l;
        bb0 = bp[0]; bb1 = bp[1]; bb2 = bp[2]; bb3 = bp[3];
        bb4 = bp[4]; bb5 = bp[5]; bb6 = bp[6]; bb7 = bp[7];
    }
    for (int node = blockIdx.x * 4 + wv; node < nN; node += gridDim.x * 4) {
        int e0 = rowptr[node];
        int e1 = rowptr[node + 1];
        float a0 = 0, a1 = 0, a2 = 0, a3 = 0, a4 = 0, a5 = 0, a6 = 0, a7 = 0;
        for (int e = e0 + par; e < e1; e += 8) {
            int s = csr_src[e];
            uint4 hv = hin[s * 8 + l];
            a0 += bf_lo(hv.x); a1 += bf_hi(hv.x);
            a2 += bf_lo(hv.y); a3 += bf_hi(hv.y);
            a4 += bf_lo(hv.z); a5 += bf_hi(hv.z);
            a6 += bf_lo(hv.w); a7 += bf_hi(hv.w);
        }
        // reduce across the 8 par-groups (lanes 8 apart)
        a0 += __shfl_down(a0, 32); a1 += __shfl_down(a1, 32);
        a2 += __shfl_down(a2, 32); a3 += __shfl_down(a3, 32);
        a4 += __shfl_down(a4, 32); a5 += __shfl_down(a5, 32);
        a6 += __shfl_down(a6, 32); a7 += __shfl_down(a7, 32);
        a0 += __shfl_down(a0, 16); a1 += __shfl_down(a1, 16);
        a2 += __shfl_down(a2, 16); a3 += __shfl_down(a3, 16);
        a4 += __shfl_down(a4, 16); a5 += __shfl_down(a5, 16);
        a6 += __shfl_down(a6, 16); a7 += __shfl_down(a7, 16);
        a0 += __shfl_down(a0, 8);  a1 += __shfl_down(a1, 8);
        a2 += __shfl_down(a2, 8);  a3 += __shfl_down(a3, 8);
        a4 += __shfl_down(a4, 8);  a5 += __shfl_down(a5, 8);
        a6 += __shfl_down(a6, 8);  a7 += __shfl_down(a7, 8);
        if (par == 0) {
            float dn = rsqrtf((float)(e1 - e0 + 1));
            uint4 hs = hin[node * 8 + l];
            a0 = (a0 + bf_lo(hs.x)) * dn; a1 = (a1 + bf_hi(hs.x)) * dn;
            a2 = (a2 + bf_lo(hs.y)) * dn; a3 = (a3 + bf_hi(hs.y)) * dn;
            a4 = (a4 + bf_lo(hs.z)) * dn; a5 = (a5 + bf_hi(hs.z)) * dn;
            a6 = (a6 + bf_lo(hs.w)) * dn; a7 = (a7 + bf_hi(hs.w)) * dn;
            if (EPI) {
                a0 = fmaxf(a0 + bb0, 0.0f) * dn; a1 = fmaxf(a1 + bb1, 0.0f) * dn;
                a2 = fmaxf(a2 + bb2, 0.0f) * dn; a3 = fmaxf(a3 + bb3, 0.0f) * dn;
                a4 = fmaxf(a4 + bb4, 0.0f) * dn; a5 = fmaxf(a5 + bb5, 0.0f) * dn;
                a6 = fmaxf(a6 + bb6, 0.0f) * dn; a7 = fmaxf(a7 + bb7, 0.0f) * dn;
            }
            hout[node * 8 + l] = make_uint4(pack2(a0, a1), pack2(a2, a3),
                                            pack2(a4, a5), pack2(a6, a7));
        }
    }
}

// ---------------- lin2pool: colsum += relu(z2' @ W2 + b2) via MFMA, never stores h2 ----------------
// Tile = 16 nodes. C layout (m89-verified): col=lane&15, row=(lane>>4)*4+reg.
__global__ void lin2pool_kernel(const uint2* __restrict__ z2, const float* __restrict__ W2,
                                const float* __restrict__ b2, float* __restrict__ colsumB,
                                int nTiles) {
    int tid = threadIdx.x;
    int lane = tid & 63;
    int wv = tid >> 6;
    int l16 = lane & 15;
    int kg = lane >> 4;  // 0..3

    // B fragments: 2 k-steps x 4 j-tiles; lane holds B[k = ks*32+kg*8+r][j = t*16+l16]
    bf16x8 Bf[2][4];
#pragma unroll
    for (int ks = 0; ks < 2; ++ks)
#pragma unroll
        for (int t = 0; t < 4; ++t) {
            bf16x8 bb;
#pragma unroll
            for (int r = 0; r < 8; ++r) {
                int k = ks * 32 + kg * 8 + r;
                bb[r] = (short)bf16r(W2[k * 64 + t * 16 + l16]);
            }
            Bf[ks][t] = bb;
        }
    float bbias[4];
#pragma unroll
    for (int t = 0; t < 4; ++t) bbias[t] = b2[t * 16 + l16];

    float colacc[4][4];
#pragma unroll
    for (int t = 0; t < 4; ++t)
#pragma unroll
        for (int r = 0; r < 4; ++r) colacc[t][r] = 0.0f;

    for (int tile = blockIdx.x * 4 + wv; tile < nTiles; tile += gridDim.x * 4) {
        int nodeBase = tile * 16;
        const uint4* zrow = (const uint4*)(z2 + (size_t)(nodeBase + l16) * 16);
        uint4 A0u = zrow[kg];
        uint4 A1u = zrow[4 + kg];
        union { uint4 u; bf16x8 b; } c0, c1;
        c0.u = A0u; c1.u = A1u;
        f32x4 acc0 = {0, 0, 0, 0}, acc1 = {0, 0, 0, 0}, acc2 = {0, 0, 0, 0}, acc3 = {0, 0, 0, 0};
        acc0 = __builtin_amdgcn_mfma_f32_16x16x32_bf16(c0.b, Bf[0][0], acc0, 0, 0, 0);
        acc1 = __builtin_amdgcn_mfma_f32_16x16x32_bf16(c0.b, Bf[0][1], acc1, 0, 0, 0);
        acc2 = __builtin_amdgcn_mfma_f32_16x16x32_bf16(c0.b, Bf[0][2], acc2, 0, 0, 0);
        acc3 = __builtin_amdgcn_mfma_f32_16x16x32_bf16(c0.b, Bf[0][3], acc3, 0, 0, 0);
        acc0 = __builtin_amdgcn_mfma_f32_16x16x32_bf16(c1.b, Bf[1][0], acc0, 0, 0, 0);
        acc1 = __builtin_amdgcn_mfma_f32_16x16x32_bf16(c1.b, Bf[1][1], acc1, 0, 0, 0);
        acc2 = __builtin_amdgcn_mfma_f32_16x16x32_bf16(c1.b, Bf[1][2], acc2, 0, 0, 0);
        acc3 = __builtin_amdgcn_mfma_f32_16x16x32_bf16(c1.b, Bf[1][3], acc3, 0, 0, 0);
#pragma unroll
        for (int r = 0; r < 4; ++r) {
            colacc[0][r] += fmaxf(acc0[r] + bbias[0], 0.0f);
            colacc[1][r] += fmaxf(acc1[r] + bbias[1], 0.0f);
            colacc[2][r] += fmaxf(acc2[r] + bbias[2], 0.0f);
            colacc[3][r] += fmaxf(acc3[r] + bbias[3], 0.0f);
        }
    }
    float s[4];
#pragma unroll
    for (int t = 0; t < 4; ++t) {
        s[t] = colacc[t][0] + colacc[t][1] + colacc[t][2] + colacc[t][3];
        s[t] += __shfl_down(s[t], 32);
        s[t] += __shfl_down(s[t], 16);
    }
    __shared__ float sm[4][64];
    if (lane < 16) {
#pragma unroll
        for (int t = 0; t < 4; ++t) sm[wv][t * 16 + lane] = s[t];
    }
    __syncthreads();
    if (tid < 64) {
        float v = sm[0][tid] + sm[1][tid] + sm[2][tid] + sm[3][tid];
        atomicAdd(&colsumB[(blockIdx.x & 15) * 64 + tid], v);
    }
}

// ---------------- gfeat: block-reduced column sums, striped atomic banks ----------------
__global__ void gfeat_kernel(const float* __restrict__ x, float* __restrict__ gsB, int nN) {
    int tid = threadIdx.x;
    int i = blockIdx.x * 256 + tid;
    float s0 = 0, s1 = 0, s2 = 0, s3 = 0, s4 = 0, s5 = 0;
    if (i < nN) {
        const float* xr = x + i * 5;
        float x0 = xr[0], x1 = xr[1], x2 = xr[2], x3 = xr[3], x4 = xr[4];
        float m = (x2 == 1.0f) ? 1.0f : 0.0f;
        s0 = x0 * m; s1 = x1 * m; s2 = x2; s3 = x3; s4 = x4; s5 = m;
    }
#pragma unroll
    for (int off = 32; off > 0; off >>= 1) {
        s0 += __shfl_down(s0, off);
        s1 += __shfl_down(s1, off);
        s2 += __shfl_down(s2, off);
        s3 += __shfl_down(s3, off);
        s4 += __shfl_down(s4, off);
        s5 += __shfl_down(s5, off);
    }
    __shared__ float smg[4][6];
    if ((tid & 63) == 0) {
        int w = tid >> 6;
        smg[w][0] = s0; smg[w][1] = s1; smg[w][2] = s2;
        smg[w][3] = s3; smg[w][4] = s4; smg[w][5] = s5;
    }
    __syncthreads();
    if (tid < 6) {
        float s = smg[0][tid] + smg[1][tid] + smg[2][tid] + smg[3][tid];
        atomicAdd(&gsB[(blockIdx.x & 15) * 16 + tid], s);
    }
}

// ---------------- head: reduce striped sums; MLP 71->32->2 -> 2+4*sigmoid ----------------
__global__ void head_kernel(const float* __restrict__ colsumB, const float* __restrict__ gsB,
                            const float* __restrict__ Wp1, const float* __restrict__ bp1,
                            const float* __restrict__ Wp2, const float* __restrict__ bp2,
                            const int* __restrict__ T, const int* __restrict__ Tmax,
                            float* __restrict__ out) {
    __shared__ float e[71];
    __shared__ float gsum[6];
    __shared__ float hid[32];
    int tid = threadIdx.x;
    if (tid < 64) {
        float s = 0.0f;
#pragma unroll
        for (int r = 0; r < 16; ++r) s += colsumB[r * 64 + tid];
        e[tid] = s * (1.0f / (float)N_NODES_C);
    } else if (tid < 70) {
        int k = tid - 64;
        float s = 0.0f;
#pragma unroll
        for (int r = 0; r < 16; ++r) s += gsB[r * 16 + k];
        gsum[k] = s;
    }
    __syncthreads();
    if (tid == 0) {
        e[64] = gsum[2];
        e[65] = gsum[3];
        e[66] = gsum[4];
        e[67] = gsum[3] + gsum[4];
        float m = gsum[5];
        e[68] = (m > 0.0f) ? gsum[0] / fmaxf(m, 1.0f) : 0.0f;
        e[69] = (m > 0.0f) ? gsum[1] / fmaxf(m, 1.0f) : 0.0f;
        e[70] = (float)T[0] / (float)Tmax[0];
    }
    __syncthreads();
    if (tid < 32) {
        float acc = bp1[tid];
        for (int i = 0; i < 71; ++i) acc += e[i] * Wp1[i * 32 + tid];
        hid[tid] = fmaxf(acc, 0.0f);
    }
    __syncthreads();
    if (tid < 2) {
        float acc = bp2[tid];
        for (int k = 0; k < 32; ++k) acc += hid[k] * Wp2[k * 2 + tid];
        out[tid] = 2.0f + 4.0f / (1.0f + expf(-acc));
    }
}

extern "C" void kernel_launch(void* const* d_in, const int* in_sizes, int n_in,
                              void* d_out, int out_size, void* d_ws, size_t ws_size,
                              hipStream_t stream) {
    const float* x    = (const float*)d_in[0];
    const int*   ei   = (const int*)d_in[1];
    const float* W1   = (const float*)d_in[2];
    const float* b1   = (const float*)d_in[3];
    const float* W2   = (const float*)d_in[4];
    const float* b2   = (const float*)d_in[5];
    const float* Wp1  = (const float*)d_in[6];
    const float* bp1  = (const float*)d_in[7];
    const float* Wp2  = (const float*)d_in[8];
    const float* bp2  = (const float*)d_in[9];
    const int*   T    = (const int*)d_in[10];
    const int*   Tmax = (const int*)d_in[11];
    float* out = (float*)d_out;

    const int nN = N_NODES_C;
    const int nE = N_EDGES_C;
    const int* src = ei;
    const int* dst = ei + nE;

    char* ws = (char*)d_ws;
    int*    cnt     = (int*)   (ws + 0);           // 400000
    int*    fill    = (int*)   (ws + 400000);      // 400000
    float*  colsumB = (float*) (ws + 800000);      // 16*64*4 = 4096
    float*  gsB     = (float*) (ws + 804096);      // 16*16*4 = 1024
    int*    bsum    = (int*)   (ws + 805120);      // 512
    int*    boff    = (int*)   (ws + 805632);      // 512
    int*    rowptr  = (int*)   (ws + 806144);      // 400016
    float*  dis     = (float*) (ws + 1206160);     // 400000
    int*    csr_src = (int*)   (ws + 1606160);     // 4.8 MB (src only)
    uint32* hlin1   = (uint32*)(ws + 6406160);     // 12.8 MB bf16 [N][64], pre-scaled by dis
    uint32* h1      = (uint32*)(ws + 19206160);    // 12.8 MB bf16, pre-scaled by dis
    uint32* z2      = (uint32*)(ws + 32006160);    // 12.8 MB bf16 (= dis*(agg+self))

    hipMemsetAsync(ws, 0, 805120, stream);  // cnt + fill + colsumB + gsB

    const int nb = (nN + 1023) / 1024;  // 98

    // CSR build (structure shared by both layers; no weights stored)
    deg_kernel<<<(nE / 4 + 255) / 256, 256, 0, stream>>>((const int4*)dst, cnt, nE / 4);
    bsum_kernel<<<nb, 256, 0, stream>>>(cnt, bsum, nN);
    bscan_kernel<<<1, 128, 0, stream>>>(bsum, boff, nb);
    scan_block_kernel<<<nb, 256, 0, stream>>>(cnt, boff, rowptr, dis, nN);
    bin_kernel<<<(nE + 255) / 256, 256, 0, stream>>>(src, dst, rowptr, fill, csr_src, nE);

    // layer 1: lin1 (pre-scaled bf16) + unweighted gather (+b1, relu, re-scale) -> h1'
    lin1_kernel<<<1024, 256, 0, stream>>>(x, W1, dis, hlin1, nN);
    gather_kernel<true><<<2048, 256, 0, stream>>>(rowptr, csr_src, (const uint4*)hlin1, b1,
                                                  (uint4*)h1, nN);

    // layer 2: gather z2' = dis*(agg(h1')+h1'); then relu(z2'@W2+b2) pooled via MFMA
    gather_kernel<false><<<2048, 256, 0, stream>>>(rowptr, csr_src, (const uint4*)h1, nullptr,
                                                   (uint4*)z2, nN);
    lin2pool_kernel<<<512, 256, 0, stream>>>((const uint2*)z2, W2, b2, colsumB, nN / 16);

    // global features (independent, reads x)
    gfeat_kernel<<<(nN + 255) / 256, 256, 0, stream>>>(x, gsB, nN);

    // head MLP
    head_kernel<<<1, 128, 0, stream>>>(colsumB, gsB, Wp1, bp1, Wp2, bp2, T, Tmax, out);
}